// Round 1
// baseline (110.670 us; speedup 1.0000x reference)
//
#include <hip/hip_runtime.h>
#include <math.h>

// Problem constants (from reference setup_inputs)
static constexpr int B_   = 32;    // batch
static constexpr int T_   = 336;   // time
static constexpr int C_   = 7;     // channels (m)
static constexpr int N_   = 5;     // shapelets per bank
static constexpr int XPAD = 337;   // padded LDS row stride (+1 to break bank conflicts)
static constexpr int PB   = 140;   // 4 banks * 35 cols per batch row
// d_out layout: out[32*10] | dists[32*140] | probs[32*140] | loss[1]
static constexpr int DIST_OFF = 320;
static constexpr int PROB_OFF = 320 + 4480;
static constexpr int LOSS_OFF = 9280;

template <int L>
__device__ __forceinline__ void bank_compute(const float* __restrict__ xs,
                                             const float* __restrict__ wsm,
                                             unsigned* __restrict__ dminS)
{
    constexpr int TT = T_ - L + 1;   // number of windows
    const int tid  = threadIdx.x;
    const int lane = tid & 63;
    for (int m = 0; m < C_; ++m) {
        const float* __restrict__ xr = xs  + m * XPAD;
        const float* __restrict__ wr = wsm + m * L;
        float best = INFINITY;       // min over t of SUM of |diff| (divide by L later)
        for (int tt = tid; tt < TT; tt += 256) {
            float s0 = 0.f, s1 = 0.f;
            #pragma unroll
            for (int j = 0; j + 1 < L; j += 2) {
                s0 += fabsf(xr[tt + j]     - wr[j]);
                s1 += fabsf(xr[tt + j + 1] - wr[j + 1]);
            }
            if (L & 1) s0 += fabsf(xr[tt + L - 1] - wr[L - 1]);
            best = fminf(best, s0 + s1);
        }
        #pragma unroll
        for (int off = 32; off; off >>= 1)
            best = fminf(best, __shfl_down(best, off, 64));
        if (lane == 0)
            atomicMin(&dminS[m], __float_as_uint(best));  // non-negative: uint order == float order
    }
}

__global__ __launch_bounds__(256)
void k_shapelet(const float* __restrict__ x,
                const float* __restrict__ w0, const float* __restrict__ w1,
                const float* __restrict__ w2, const float* __restrict__ w3,
                float* __restrict__ out)
{
    __shared__ float    xs[C_ * XPAD];     // normalized x[b], padded rows
    __shared__ float    wsm[C_ * 168];     // this block's shapelet (n) for its bank
    __shared__ unsigned dminS[C_];

    const int bid  = blockIdx.x;           // 640 = 32 * 4 * 5
    const int b    = bid / 20;
    const int rem  = bid % 20;
    const int bank = rem / 5;
    const int n    = rem % 5;
    const int tid  = threadIdx.x;

    int l; const float* wsrc;
    switch (bank) {
        case 0:  l = 34;  wsrc = w0; break;
        case 1:  l = 68;  wsrc = w1; break;
        case 2:  l = 101; wsrc = w2; break;
        default: l = 168; wsrc = w3; break;
    }

    // ---- load + transpose x[b] (T,C) -> xs[c][t] ----
    const float* __restrict__ xb = x + (size_t)b * T_ * C_;
    for (int i = tid; i < T_ * C_; i += 256) {
        int t = i / C_, c = i - t * C_;    // memory is [t][c]
        xs[c * XPAD + t] = xb[i];
    }
    // ---- load this block's shapelet: w[bank][n] (C, l) ----
    const float* __restrict__ wn = wsrc + (size_t)n * C_ * l;
    for (int i = tid; i < C_ * l; i += 256) wsm[i] = wn[i];
    if (tid < C_) dminS[tid] = 0x7F800000u;  // +inf bits
    __syncthreads();

    // ---- in-block normalization, per channel row (ddof=1) ----
    const int wv   = tid >> 6;
    const int lane = tid & 63;
    for (int r = wv; r < C_; r += 4) {
        float* row = xs + r * XPAD;
        float s = 0.f;
        for (int t = lane; t < T_; t += 64) s += row[t];
        #pragma unroll
        for (int off = 32; off; off >>= 1) s += __shfl_down(s, off, 64);
        s = __shfl(s, 0, 64);
        const float mu = s / (float)T_;
        float sq = 0.f;
        for (int t = lane; t < T_; t += 64) { float d = row[t] - mu; sq += d * d; }
        #pragma unroll
        for (int off = 32; off; off >>= 1) sq += __shfl_down(sq, off, 64);
        sq = __shfl(sq, 0, 64);
        const float sd  = sqrtf(sq / (float)(T_ - 1));
        const float inv = 1.f / (sd + 1e-8f);
        for (int t = lane; t < T_; t += 64) row[t] = (row[t] - mu) * inv;
    }
    __syncthreads();

    // ---- shapelet distances: min over windows of mean |xn - w| ----
    switch (bank) {
        case 0:  bank_compute<34 >(xs, wsm, dminS); break;
        case 1:  bank_compute<68 >(xs, wsm, dminS); break;
        case 2:  bank_compute<101>(xs, wsm, dminS); break;
        default: bank_compute<168>(xs, wsm, dminS); break;
    }
    __syncthreads();

    if (tid < C_) {
        float d = __uint_as_float(dminS[tid]) / (float)l;  // sum -> mean (monotone, exact)
        float p = expf(-d * d);                            // EPS_GATE = 1.0
        int col = bank * 35 + n * C_ + tid;
        out[DIST_OFF + b * PB + col] = d;
        out[PROB_OFF + b * PB + col] = p;
    }
}

__global__ __launch_bounds__(320)
void k_out(const float* __restrict__ W_out, float* __restrict__ out)
{
    __shared__ float red[5];
    const int i = threadIdx.x;                 // 320 threads = 32 b * 10 k
    const float* __restrict__ probs = out + PROB_OFF;

    // loss partial: 0.1 * mean(|W_out|), 10*140 = 1400 elems
    float ls = 0.f;
    for (int j = i; j < 1400; j += 320) ls += fabsf(W_out[j]);
    const int lane = i & 63, wv = i >> 6;
    #pragma unroll
    for (int off = 32; off; off >>= 1) ls += __shfl_down(ls, off, 64);
    if (lane == 0) red[wv] = ls;

    // out[b,k] = sum_j probs[b,j] * W_out[k,j]
    const int b = i / 10, k = i % 10;
    const float* __restrict__ pb = probs + b * PB;
    const float* __restrict__ wk = W_out + k * PB;
    float s = 0.f;
    #pragma unroll 4
    for (int j = 0; j < PB; ++j) s += pb[j] * wk[j];
    out[b * 10 + k] = s;

    __syncthreads();
    if (i == 0) {
        float tot = red[0] + red[1] + red[2] + red[3] + red[4];
        out[LOSS_OFF] = 0.1f * tot / 1400.0f;
    }
}

extern "C" void kernel_launch(void* const* d_in, const int* in_sizes, int n_in,
                              void* d_out, int out_size, void* d_ws, size_t ws_size,
                              hipStream_t stream)
{
    const float* x     = (const float*)d_in[0];
    const float* w0    = (const float*)d_in[1];
    const float* w1    = (const float*)d_in[2];
    const float* w2    = (const float*)d_in[3];
    const float* w3    = (const float*)d_in[4];
    const float* W_out = (const float*)d_in[5];
    float* out = (float*)d_out;

    hipLaunchKernelGGL(k_shapelet, dim3(B_ * 4 * N_), dim3(256), 0, stream,
                       x, w0, w1, w2, w3, out);
    hipLaunchKernelGGL(k_out, dim3(1), dim3(320), 0, stream, W_out, out);
}

// Round 2
// 92.488 us; speedup vs baseline: 1.1966x; 1.1966x over previous
//
#include <hip/hip_runtime.h>
#include <math.h>

// Problem constants (from reference setup_inputs)
static constexpr int B_ = 32;    // batch
static constexpr int T_ = 336;   // time
static constexpr int C_ = 7;     // channels (m)
static constexpr int N_ = 5;     // shapelets per bank
static constexpr int PB = 140;   // 4 banks * 35 cols per batch row
// d_out layout: out[32*10] | dists[32*140] | probs[32*140] | loss[1]
static constexpr int DIST_OFF = 320;
static constexpr int PROB_OFF = 320 + 4480;   // 4800
static constexpr int LOSS_OFF = 9280;

// One block handles (b, bank, m): all N_ shapelets, all windows, one channel.
// xs[t+j] is read from LDS ONCE per (t,j) and reused for all 5 shapelets;
// w is read via wave-uniform global indices -> scalar loads (s_load), off the
// LDS pipe entirely.
template <int L>
__device__ __forceinline__ void bank_body(const float* __restrict__ xs,
                                          const float* __restrict__ w,  // global, + m*L already? no: base
                                          int m,
                                          unsigned* __restrict__ dminS)
{
    constexpr int TT = T_ - L + 1;
    const int tid  = threadIdx.x;
    const int lane = tid & 63;

    const float* __restrict__ w0 = w + (0 * C_ + m) * L;
    const float* __restrict__ w1 = w + (1 * C_ + m) * L;
    const float* __restrict__ w2 = w + (2 * C_ + m) * L;
    const float* __restrict__ w3 = w + (3 * C_ + m) * L;
    const float* __restrict__ w4 = w + (4 * C_ + m) * L;

    float b0 = INFINITY, b1 = INFINITY, b2 = INFINITY, b3 = INFINITY, b4 = INFINITY;
    for (int t0 = tid; t0 < TT; t0 += 256) {
        float a0 = 0.f, a1 = 0.f, a2 = 0.f, a3 = 0.f, a4 = 0.f;
        #pragma unroll 4
        for (int j = 0; j < L; ++j) {
            const float xv = xs[t0 + j];          // 1 LDS read, reused 5x
            a0 += fabsf(xv - w0[j]);              // w*: wave-uniform -> s_load
            a1 += fabsf(xv - w1[j]);
            a2 += fabsf(xv - w2[j]);
            a3 += fabsf(xv - w3[j]);
            a4 += fabsf(xv - w4[j]);
        }
        b0 = fminf(b0, a0); b1 = fminf(b1, a1); b2 = fminf(b2, a2);
        b3 = fminf(b3, a3); b4 = fminf(b4, a4);
    }
    #pragma unroll
    for (int off = 32; off; off >>= 1) {
        b0 = fminf(b0, __shfl_down(b0, off, 64));
        b1 = fminf(b1, __shfl_down(b1, off, 64));
        b2 = fminf(b2, __shfl_down(b2, off, 64));
        b3 = fminf(b3, __shfl_down(b3, off, 64));
        b4 = fminf(b4, __shfl_down(b4, off, 64));
    }
    if (lane == 0) {   // min of non-negative floats: uint order == float order
        atomicMin(&dminS[0], __float_as_uint(b0));
        atomicMin(&dminS[1], __float_as_uint(b1));
        atomicMin(&dminS[2], __float_as_uint(b2));
        atomicMin(&dminS[3], __float_as_uint(b3));
        atomicMin(&dminS[4], __float_as_uint(b4));
    }
}

__global__ __launch_bounds__(256)
void k_main(const float* __restrict__ x,
            const float* __restrict__ w0, const float* __restrict__ w1,
            const float* __restrict__ w2, const float* __restrict__ w3,
            float* __restrict__ out)
{
    __shared__ float    xs[T_];     // one normalized channel row
    __shared__ float    red[8];
    __shared__ unsigned dminS[N_];

    const int bid  = blockIdx.x;    // 896 = 32 * 4 * 7
    const int b    = bid / (4 * C_);
    const int rem  = bid % (4 * C_);
    const int bank = rem / C_;
    const int m    = rem % C_;
    const int tid  = threadIdx.x;
    const int lane = tid & 63;
    const int wv   = tid >> 6;

    int l; const float* wsrc;
    switch (bank) {
        case 0:  l = 34;  wsrc = w0; break;
        case 1:  l = 68;  wsrc = w1; break;
        case 2:  l = 101; wsrc = w2; break;
        default: l = 168; wsrc = w3; break;
    }

    // ---- load channel row: x[b, t, m], stride C_ ----
    const float* __restrict__ xb = x + (size_t)b * T_ * C_ + m;
    for (int t = tid; t < T_; t += 256) xs[t] = xb[(size_t)t * C_];
    if (tid < N_) dminS[tid] = 0x7F800000u;   // +inf bits
    __syncthreads();

    // ---- two-pass normalize (ddof=1), all 4 waves cooperate ----
    float s = 0.f;
    for (int t = tid; t < T_; t += 256) s += xs[t];
    #pragma unroll
    for (int off = 32; off; off >>= 1) s += __shfl_down(s, off, 64);
    if (lane == 0) red[wv] = s;
    __syncthreads();
    const float mu = (red[0] + red[1] + red[2] + red[3]) / (float)T_;

    float q = 0.f;
    for (int t = tid; t < T_; t += 256) { float d = xs[t] - mu; q += d * d; }
    #pragma unroll
    for (int off = 32; off; off >>= 1) q += __shfl_down(q, off, 64);
    if (lane == 0) red[4 + wv] = q;
    __syncthreads();
    const float sd  = sqrtf((red[4] + red[5] + red[6] + red[7]) / (float)(T_ - 1));
    const float inv = 1.f / (sd + 1e-8f);
    for (int t = tid; t < T_; t += 256) xs[t] = (xs[t] - mu) * inv;
    __syncthreads();

    // ---- shapelet distances ----
    switch (bank) {
        case 0:  bank_body<34 >(xs, wsrc, m, dminS); break;
        case 1:  bank_body<68 >(xs, wsrc, m, dminS); break;
        case 2:  bank_body<101>(xs, wsrc, m, dminS); break;
        default: bank_body<168>(xs, wsrc, m, dminS); break;
    }
    __syncthreads();

    if (tid < N_) {
        const float d = __uint_as_float(dminS[tid]) / (float)l;  // sum -> mean
        const float p = expf(-d * d);                            // EPS_GATE = 1.0
        const int col = bank * 35 + tid * C_ + m;                // n = tid
        out[DIST_OFF + b * PB + col] = d;
        out[PROB_OFF + b * PB + col] = p;
    }
}

__global__ __launch_bounds__(320)
void k_out(const float* __restrict__ W_out, float* __restrict__ out)
{
    __shared__ float red[5];
    const int i = threadIdx.x;                 // 320 threads = 32 b * 10 k
    const float* __restrict__ probs = out + PROB_OFF;

    // loss partial: 0.1 * mean(|W_out|), 10*140 = 1400 elems
    float ls = 0.f;
    for (int j = i; j < 1400; j += 320) ls += fabsf(W_out[j]);
    const int lane = i & 63, wv = i >> 6;
    #pragma unroll
    for (int off = 32; off; off >>= 1) ls += __shfl_down(ls, off, 64);
    if (lane == 0) red[wv] = ls;

    // out[b,k] = sum_j probs[b,j] * W_out[k,j]
    const int b = i / 10, k = i % 10;
    const float* __restrict__ pb = probs + b * PB;
    const float* __restrict__ wk = W_out + k * PB;
    float s = 0.f;
    #pragma unroll 4
    for (int j = 0; j < PB; ++j) s += pb[j] * wk[j];
    out[b * 10 + k] = s;

    __syncthreads();
    if (i == 0) {
        float tot = red[0] + red[1] + red[2] + red[3] + red[4];
        out[LOSS_OFF] = 0.1f * tot / 1400.0f;
    }
}

extern "C" void kernel_launch(void* const* d_in, const int* in_sizes, int n_in,
                              void* d_out, int out_size, void* d_ws, size_t ws_size,
                              hipStream_t stream)
{
    const float* x     = (const float*)d_in[0];
    const float* w0    = (const float*)d_in[1];
    const float* w1    = (const float*)d_in[2];
    const float* w2    = (const float*)d_in[3];
    const float* w3    = (const float*)d_in[4];
    const float* W_out = (const float*)d_in[5];
    float* out = (float*)d_out;

    hipLaunchKernelGGL(k_main, dim3(B_ * 4 * C_), dim3(256), 0, stream,
                       x, w0, w1, w2, w3, out);
    hipLaunchKernelGGL(k_out, dim3(1), dim3(320), 0, stream, W_out, out);
}